// Round 3
// baseline (456.799 us; speedup 1.0000x reference)
//
#include <hip/hip_runtime.h>
#include <hip/hip_bf16.h>

#define NNODES 30000
#define NEDGES 480000
#define HC 256
#define NEG_SLOPE 0.2f
#define NPART 8
#define EPP 60000                 // NEDGES / NPART
#define PN (NPART * NNODES)       // 240000 part-major degree entries
#define SCAN_CHUNK 1024
#define NCHUNK2 235               // ceil(PN / 1024)
#define CPP 235                   // ceil(EPP / 256) chunks per part
#define NFE 7680000               // NNODES * HC

typedef _Float16 half8 __attribute__((ext_vector_type(8)));
typedef _Float16 half4v __attribute__((ext_vector_type(4)));
typedef float floatx4 __attribute__((ext_vector_type(4)));

// ---------------- CSR build (XCD-partitioned) ----------------
// Edges split into 8 parts of 60000; blockIdx.x % 8 selects the part so all
// blocks touching part p's deg/cur/col lines land on the same XCD (round-robin
// dispatch) -> full-line accumulation in that XCD's L2, no cross-XCD write amp.

__global__ void hist_kernel(const int* __restrict__ ei, int* __restrict__ deg_dst,
                            int* __restrict__ deg_src) {
    int p = blockIdx.x & 7, c = blockIdx.x >> 3;
    int idx = c * 256 + threadIdx.x;
    if (idx >= EPP) return;
    int e = p * EPP + idx;
    int s = ei[e];
    int d = ei[NEDGES + e];
    atomicAdd(&deg_dst[p * NNODES + d], 1);
    atomicAdd(&deg_src[p * NNODES + s], 1);
}

// global exclusive scan over the part-major concatenated deg arrays (PN elems).
__global__ void scan1_kernel(const int* __restrict__ deg_dst, const int* __restrict__ deg_src,
                             int* __restrict__ rp_dst, int* __restrict__ rp_src,
                             int* __restrict__ bsum) {
    __shared__ int sh[SCAN_CHUNK];
    const int* deg = (blockIdx.y == 0) ? deg_dst : deg_src;
    int* rp = (blockIdx.y == 0) ? rp_dst : rp_src;
    int t = threadIdx.x;
    int gid = blockIdx.x * SCAN_CHUNK + t;
    int v = (gid < PN) ? deg[gid] : 0;
    sh[t] = v;
    __syncthreads();
    for (int off = 1; off < SCAN_CHUNK; off <<= 1) {
        int u = (t >= off) ? sh[t - off] : 0;
        __syncthreads();
        sh[t] += u;
        __syncthreads();
    }
    if (gid < PN) rp[gid + 1] = sh[t];
    if (t == SCAN_CHUNK - 1) bsum[blockIdx.y * 256 + blockIdx.x] = sh[t];
}

__global__ void scan2_kernel(int* __restrict__ bsum) {
    int t = threadIdx.x;
    if (t < 2) {
        int run = 0;
        for (int i = 0; i < NCHUNK2; i++) {
            int v = bsum[t * 256 + i];
            bsum[t * 256 + i] = run;
            run += v;
        }
    }
}

__global__ void scan3_kernel(int* __restrict__ rp_dst, int* __restrict__ rp_src,
                             const int* __restrict__ bsum) {
    int* rp = (blockIdx.y == 0) ? rp_dst : rp_src;
    int t = threadIdx.x;
    int gid = blockIdx.x * SCAN_CHUNK + t;
    int base = bsum[blockIdx.y * 256 + blockIdx.x];
    if (gid < PN) rp[gid + 1] += base;
    if (gid == 0) rp[0] = 0;
}

__global__ void fill_kernel(const int* __restrict__ ei, int* __restrict__ cur_dst,
                            int* __restrict__ cur_src, unsigned short* __restrict__ col_dst,
                            unsigned short* __restrict__ col_src) {
    int p = blockIdx.x & 7, c = blockIdx.x >> 3;
    int idx = c * 256 + threadIdx.x;
    if (idx >= EPP) return;
    int e = p * EPP + idx;
    int s = ei[e];
    int d = ei[NEDGES + e];
    int p0 = atomicAdd(&cur_dst[p * NNODES + d], 1);
    col_dst[p0] = (unsigned short)s;
    int p1 = atomicAdd(&cur_src[p * NNODES + s], 1);
    col_src[p1] = (unsigned short)d;
}

// ---------------- conversions ----------------

__global__ void cvt_f16(const float* __restrict__ in0, _Float16* __restrict__ out0,
                        const float* __restrict__ in1, _Float16* __restrict__ out1) {
    const float* in = blockIdx.y ? in1 : in0;
    _Float16* out = blockIdx.y ? out1 : out0;
    int i = blockIdx.x * blockDim.x + threadIdx.x;
    float4 v = ((const float4*)in)[i];
    half4v h = {(_Float16)v.x, (_Float16)v.y, (_Float16)v.z, (_Float16)v.w};
    ((half4v*)out)[i] = h;
}

__global__ void wtrans_kernel(const float* __restrict__ Wl, const float* __restrict__ Wr,
                              _Float16* __restrict__ WtL, _Float16* __restrict__ WtR) {
    __shared__ float sh[32][33];
    int e = blockIdx.z;
    const float* W = (e < 4) ? Wl + (size_t)e * 65536 : Wr + (size_t)(e - 4) * 65536;
    _Float16* Wt = (e < 4) ? WtL + (size_t)e * 65536 : WtR + (size_t)(e - 4) * 65536;
    int r0 = blockIdx.y * 32, c0 = blockIdx.x * 32;
    int x = threadIdx.x, y = threadIdx.y;  // 32 x 8
#pragma unroll
    for (int j = 0; j < 4; j++) {
        int r = y + j * 8;
        sh[r][x] = W[(size_t)(r0 + r) * 256 + c0 + x];
    }
    __syncthreads();
#pragma unroll
    for (int j = 0; j < 4; j++) {
        int nn = y + j * 8;
        Wt[(size_t)(c0 + nn) * 256 + r0 + x] = (_Float16)sh[x][nn];
    }
}

// ---------------- fp16 MFMA GEMM (4 GEMMs fused via grid.y) ----------------
// y=0: hl_a = xs@Wl[e0];  y=1: hr_a = xt@Wr[e0]
// y=2: hl_b = xt@Wl[e1];  y=3: hr_b = xs@Wr[e1]
__launch_bounds__(256)
__global__ void gemm_f16(const _Float16* __restrict__ xs, const _Float16* __restrict__ xt,
                         const _Float16* __restrict__ WtL, const _Float16* __restrict__ WtR,
                         const float* __restrict__ bl, const float* __restrict__ br,
                         _Float16* __restrict__ hbase, int e0) {
    const int y = blockIdx.y;
    const int e = e0 + (y >> 1);
    const _Float16* A = (y == 0 || y == 3) ? xs : xt;
    const bool left = (y & 1) == 0;
    const _Float16* Wt = (left ? WtL : WtR) + (size_t)e * 65536;
    const float* bvec = (left ? bl : br) + (size_t)e * HC;
    _Float16* C = hbase + (size_t)y * NFE;

    __shared__ __align__(16) _Float16 As[64 * 32];
    __shared__ __align__(16) _Float16 Bs[256 * 32];

    const int t = threadIdx.x;
    const int lane = t & 63, w = t >> 6;
    const int m0 = blockIdx.x * 64;
    const int rl = lane & 15, ch = lane >> 4;
    const int ar = t >> 2, ac = t & 3;

    floatx4 acc[4][4] = {};

    for (int k0 = 0; k0 < 256; k0 += 32) {
        half8 av = {};
        {
            int gr = m0 + ar;
            if (gr < NNODES) av = *(const half8*)(A + (size_t)gr * 256 + k0 + ac * 8);
        }
        half8 bv[4];
#pragma unroll
        for (int j = 0; j < 4; j++) {
            int n = ar + j * 64;
            bv[j] = *(const half8*)(Wt + (size_t)n * 256 + k0 + ac * 8);
        }
        __syncthreads();
        *(half8*)(As + ar * 32 + (ac ^ ((ar >> 1) & 3)) * 8) = av;
#pragma unroll
        for (int j = 0; j < 4; j++) {
            int n = ar + j * 64;
            *(half8*)(Bs + n * 32 + (ac ^ ((n >> 1) & 3)) * 8) = bv[j];
        }
        __syncthreads();

        half8 a[4], b[4];
#pragma unroll
        for (int fm = 0; fm < 4; fm++) {
            int r = fm * 16 + rl;
            a[fm] = *(const half8*)(As + r * 32 + (ch ^ ((r >> 1) & 3)) * 8);
        }
#pragma unroll
        for (int fn = 0; fn < 4; fn++) {
            int n = w * 64 + fn * 16 + rl;
            b[fn] = *(const half8*)(Bs + n * 32 + (ch ^ ((n >> 1) & 3)) * 8);
        }
#pragma unroll
        for (int fm = 0; fm < 4; fm++)
#pragma unroll
            for (int fn = 0; fn < 4; fn++)
                acc[fm][fn] = __builtin_amdgcn_mfma_f32_16x16x32_f16(a[fm], b[fn], acc[fm][fn], 0, 0, 0);
    }

#pragma unroll
    for (int fn = 0; fn < 4; fn++) {
        int colb = w * 64 + fn * 16 + rl;
        float bb = bvec[colb];
#pragma unroll
        for (int fm = 0; fm < 4; fm++) {
#pragma unroll
            for (int j = 0; j < 4; j++) {
                int row = m0 + fm * 16 + ch * 4 + j;
                if (row < NNODES) C[(size_t)row * 256 + colb] = (_Float16)(acc[fm][fn][j] + bb);
            }
        }
    }
}

// ---------------- fused attention + aggregate (2 directions via grid.y) ----------------

__device__ inline float4 ld4h(const _Float16* p) {
    half4v v = *(const half4v*)p;
    return make_float4((float)v[0], (float)v[1], (float)v[2], (float)v[3]);
}
__device__ inline void store4(float* p, float4 v) { *(float4*)p = v; }
__device__ inline void store4(_Float16* p, float4 v) {
    half4v h = {(_Float16)v.x, (_Float16)v.y, (_Float16)v.z, (_Float16)v.w};
    *(half4v*)p = h;
}

template <typename OT>
__launch_bounds__(256)
__global__ void agg_kernel(const _Float16* __restrict__ hbase,
                           const int* __restrict__ rp_dst, const unsigned short* __restrict__ col_dst,
                           const int* __restrict__ rp_src, const unsigned short* __restrict__ col_src,
                           const float* __restrict__ att, const float* __restrict__ bias,
                           OT* __restrict__ out0, OT* __restrict__ out1,
                           int e0, int do_relu) {
    const int z = blockIdx.y;
    const _Float16* hl = hbase + (size_t)z * 2 * NFE;
    const _Float16* hr = hl + NFE;
    const int* rp = z ? rp_src : rp_dst;
    const unsigned short* col = z ? col_src : col_dst;
    const float* attz = att + (size_t)(e0 + z) * HC;
    const float* biasz = bias + (size_t)(e0 + z) * HC;
    OT* out = z ? out1 : out0;

    int wave = threadIdx.x >> 6;
    int lane = threadIdx.x & 63;
    int n = blockIdx.x * 4 + wave;
    if (n >= NNODES) return;

    int c4 = lane << 2;
    float4 hr4 = ld4h(hr + (size_t)n * HC + c4);
    float4 att4 = *(const float4*)(attz + c4);
    float4 b4 = *(const float4*)(biasz + c4);

    float4 acc = make_float4(0.f, 0.f, 0.f, 0.f);
    float denom = 0.f;

#define EDGE(h4)                                                                  \
    {                                                                             \
        float4 x4 = make_float4(h4.x + hr4.x, h4.y + hr4.y, h4.z + hr4.z, h4.w + hr4.w); \
        float4 e4;                                                                \
        e4.x = x4.x > 0.f ? x4.x : NEG_SLOPE * x4.x;                              \
        e4.y = x4.y > 0.f ? x4.y : NEG_SLOPE * x4.y;                              \
        e4.z = x4.z > 0.f ? x4.z : NEG_SLOPE * x4.z;                              \
        e4.w = x4.w > 0.f ? x4.w : NEG_SLOPE * x4.w;                              \
        float v = att4.x * e4.x + att4.y * e4.y + att4.z * e4.z + att4.w * e4.w;  \
        v += __shfl_xor(v, 1);                                                    \
        v += __shfl_xor(v, 2);                                                    \
        v += __shfl_xor(v, 4);                                                    \
        float p = __expf(v);                                                      \
        denom += p;                                                               \
        acc.x += p * h4.x;                                                        \
        acc.y += p * h4.y;                                                        \
        acc.z += p * h4.z;                                                        \
        acc.w += p * h4.w;                                                        \
    }

    for (int p = 0; p < NPART; p++) {
        int beg = rp[p * NNODES + n];
        int end = rp[p * NNODES + n + 1];
        int i = beg;
        for (; i + 2 <= end; i += 2) {
            int s0 = col[i], s1 = col[i + 1];
            float4 h0 = ld4h(hl + (size_t)s0 * HC + c4);
            float4 h1 = ld4h(hl + (size_t)s1 * HC + c4);
            EDGE(h0);
            EDGE(h1);
        }
        if (i < end) {
            int s0 = col[i];
            float4 h0 = ld4h(hl + (size_t)s0 * HC + c4);
            EDGE(h0);
        }
    }
#undef EDGE

    float inv = 1.f / (denom + 1e-16f);
    float4 o;
    o.x = acc.x * inv + b4.x;
    o.y = acc.y * inv + b4.y;
    o.z = acc.z * inv + b4.z;
    o.w = acc.w * inv + b4.w;
    if (do_relu) {
        o.x = fmaxf(o.x, 0.f);
        o.y = fmaxf(o.y, 0.f);
        o.z = fmaxf(o.z, 0.f);
        o.w = fmaxf(o.w, 0.f);
    }
    store4(out + (size_t)n * HC + c4, o);
}

// ---------------- launch ----------------

extern "C" void kernel_launch(void* const* d_in, const int* in_sizes, int n_in,
                              void* d_out, int out_size, void* d_ws, size_t ws_size,
                              hipStream_t stream) {
    const float* s = (const float*)d_in[0];
    const float* t = (const float*)d_in[1];
    const float* Wl = (const float*)d_in[2];
    const float* bl = (const float*)d_in[3];
    const float* Wr = (const float*)d_in[4];
    const float* br = (const float*)d_in[5];
    const float* att = (const float*)d_in[6];
    const float* bias = (const float*)d_in[7];
    const int* ei = (const int*)d_in[8];
    float* out = (float*)d_out;

    const size_t NF = (size_t)NFE;

    // workspace layout
    _Float16* xs16 = (_Float16*)d_ws;
    _Float16* xt16 = xs16 + NF;
    _Float16* hbase = xt16 + NF;          // 4 * NF (hl_a, hr_a, hl_b, hr_b)
    _Float16* WtL = hbase + 4 * NF;       // 4*65536
    _Float16* WtR = WtL + 4 * 65536;      // 4*65536
    int* deg_dst = (int*)(WtR + 4 * 65536);   // PN
    int* deg_src = deg_dst + PN;              // PN
    int* rp_dst = deg_src + PN;               // PN+1
    int* rp_src = rp_dst + (PN + 1);          // PN+1
    int* cur_dst = rp_src + (PN + 1);         // PN
    int* cur_src = cur_dst + PN;              // PN
    int* bsum = cur_src + PN;                 // 512
    unsigned short* col_dst = (unsigned short*)(bsum + 512);  // E
    unsigned short* col_src = col_dst + NEDGES;               // E

    // ---- conversions ----
    {
        dim3 g(NF / 4 / 256, 2);
        cvt_f16<<<g, 256, 0, stream>>>(s, xs16, t, xt16);
        dim3 gw(8, 8, 8);
        wtrans_kernel<<<gw, dim3(32, 8), 0, stream>>>(Wl, Wr, WtL, WtR);
    }

    // ---- CSR build (partitioned) ----
    hipMemsetAsync(deg_dst, 0, 2 * PN * sizeof(int), stream);
    hist_kernel<<<NPART * CPP, 256, 0, stream>>>(ei, deg_dst, deg_src);
    {
        dim3 g(NCHUNK2, 2);
        scan1_kernel<<<g, SCAN_CHUNK, 0, stream>>>(deg_dst, deg_src, rp_dst, rp_src, bsum);
        scan2_kernel<<<1, 64, 0, stream>>>(bsum);
        scan3_kernel<<<g, SCAN_CHUNK, 0, stream>>>(rp_dst, rp_src, bsum);
    }
    hipMemcpyAsync(cur_dst, rp_dst, PN * sizeof(int), hipMemcpyDeviceToDevice, stream);
    hipMemcpyAsync(cur_src, rp_src, PN * sizeof(int), hipMemcpyDeviceToDevice, stream);
    fill_kernel<<<NPART * CPP, 256, 0, stream>>>(ei, cur_dst, cur_src, col_dst, col_src);

    dim3 ggemm((NNODES + 63) / 64, 4);
    dim3 gagg((NNODES + 3) / 4, 2);

    for (int l = 0; l < 2; l++) {
        int e0 = 2 * l;
        int do_relu = (l == 0) ? 1 : 0;
        gemm_f16<<<ggemm, 256, 0, stream>>>(xs16, xt16, WtL, WtR, bl, br, hbase, e0);
        if (l == 0)
            agg_kernel<_Float16><<<gagg, 256, 0, stream>>>(hbase, rp_dst, col_dst, rp_src, col_src,
                                                           att, bias, xs16, xt16, e0, do_relu);
        else
            agg_kernel<float><<<gagg, 256, 0, stream>>>(hbase, rp_dst, col_dst, rp_src, col_src,
                                                        att, bias, out, out + NF, e0, do_relu);
    }
}

// Round 4
// 435.737 us; speedup vs baseline: 1.0483x; 1.0483x over previous
//
#include <hip/hip_runtime.h>
#include <hip/hip_bf16.h>

#define NNODES 30000
#define NEDGES 480000
#define HC 256
#define NEG_SLOPE 0.2f
#define NPART 8
#define EPP 60000                 // NEDGES / NPART
#define PN (NPART * NNODES)       // 240000
#define SCAN_CHUNK 1024
#define NCHUNK2 235               // ceil(PN / 1024)
#define CPP 235                   // ceil(EPP / 256)
#define NFE 7680000               // NNODES * HC

typedef _Float16 half8 __attribute__((ext_vector_type(8)));
typedef _Float16 h4v __attribute__((ext_vector_type(4)));
typedef _Float16 h2 __attribute__((ext_vector_type(2)));
typedef float floatx4 __attribute__((ext_vector_type(4)));

// ---------------- prep: weight transpose+cvt (blocks 0..511) | edge histogram (rest) ----------------

__global__ void prep_kernel(const float* __restrict__ Wl, const float* __restrict__ Wr,
                            _Float16* __restrict__ WtL, _Float16* __restrict__ WtR,
                            const int* __restrict__ ei, int* __restrict__ deg_dst,
                            int* __restrict__ deg_src) {
    __shared__ float sh[32][33];
    int b = blockIdx.x;
    if (b < 512) {
        int e = b >> 6;
        int r0 = ((b >> 3) & 7) * 32, c0 = (b & 7) * 32;
        const float* W = (e < 4) ? Wl + (size_t)e * 65536 : Wr + (size_t)(e - 4) * 65536;
        _Float16* Wt = (e < 4) ? WtL + (size_t)e * 65536 : WtR + (size_t)(e - 4) * 65536;
        int x = threadIdx.x & 31, y = threadIdx.x >> 5;  // 32 x 8
#pragma unroll
        for (int j = 0; j < 4; j++) {
            int r = y + j * 8;
            sh[r][x] = W[(size_t)(r0 + r) * 256 + c0 + x];
        }
        __syncthreads();
#pragma unroll
        for (int j = 0; j < 4; j++) {
            int nn = y + j * 8;
            Wt[(size_t)(c0 + nn) * 256 + r0 + x] = (_Float16)sh[x][nn];
        }
    } else {
        b -= 512;
        int p = b & 7, c = b >> 3;
        int idx = c * 256 + threadIdx.x;
        if (idx >= EPP) return;
        int e = p * EPP + idx;
        int s = ei[e];
        int d = ei[NEDGES + e];
        atomicAdd(&deg_dst[p * NNODES + d], 1);
        atomicAdd(&deg_src[p * NNODES + s], 1);
    }
}

// ---------------- scans (also produce cur = exclusive offsets) ----------------

__global__ void scan1_kernel(const int* __restrict__ deg_dst, const int* __restrict__ deg_src,
                             int* __restrict__ rp_dst, int* __restrict__ rp_src,
                             int* __restrict__ cur_dst, int* __restrict__ cur_src,
                             int* __restrict__ bsum) {
    __shared__ int sh[SCAN_CHUNK];
    const int* deg = (blockIdx.y == 0) ? deg_dst : deg_src;
    int* rp = (blockIdx.y == 0) ? rp_dst : rp_src;
    int* cur = (blockIdx.y == 0) ? cur_dst : cur_src;
    int t = threadIdx.x;
    int gid = blockIdx.x * SCAN_CHUNK + t;
    int v = (gid < PN) ? deg[gid] : 0;
    sh[t] = v;
    __syncthreads();
    for (int off = 1; off < SCAN_CHUNK; off <<= 1) {
        int u = (t >= off) ? sh[t - off] : 0;
        __syncthreads();
        sh[t] += u;
        __syncthreads();
    }
    if (gid < PN) {
        rp[gid + 1] = sh[t];
        cur[gid] = sh[t] - v;
    }
    if (t == SCAN_CHUNK - 1) bsum[blockIdx.y * 256 + blockIdx.x] = sh[t];
}

__global__ void scan2_kernel(int* __restrict__ bsum) {
    int t = threadIdx.x;
    if (t < 2) {
        int run = 0;
        for (int i = 0; i < NCHUNK2; i++) {
            int v = bsum[t * 256 + i];
            bsum[t * 256 + i] = run;
            run += v;
        }
    }
}

__global__ void scan3_kernel(int* __restrict__ rp_dst, int* __restrict__ rp_src,
                             int* __restrict__ cur_dst, int* __restrict__ cur_src,
                             const int* __restrict__ bsum) {
    int* rp = (blockIdx.y == 0) ? rp_dst : rp_src;
    int* cur = (blockIdx.y == 0) ? cur_dst : cur_src;
    int t = threadIdx.x;
    int gid = blockIdx.x * SCAN_CHUNK + t;
    int base = bsum[blockIdx.y * 256 + blockIdx.x];
    if (gid < PN) {
        rp[gid + 1] += base;
        cur[gid] += base;
    }
    if (gid == 0) rp[0] = 0;
}

__global__ void fill_kernel(const int* __restrict__ ei, int* __restrict__ cur_dst,
                            int* __restrict__ cur_src, unsigned short* __restrict__ col_dst,
                            unsigned short* __restrict__ col_src) {
    int p = blockIdx.x & 7, c = blockIdx.x >> 3;
    int idx = c * 256 + threadIdx.x;
    if (idx >= EPP) return;
    int e = p * EPP + idx;
    int s = ei[e];
    int d = ei[NEDGES + e];
    int p0 = atomicAdd(&cur_dst[p * NNODES + d], 1);
    col_dst[p0] = (unsigned short)s;
    int p1 = atomicAdd(&cur_src[p * NNODES + s], 1);
    col_src[p1] = (unsigned short)d;
}

// ---------------- fp16 MFMA GEMM (4 GEMMs fused via grid.y; A-dtype templated) ----------------
// y=0: hl_a = xs@Wl[e0];  y=1: hr_a = xt@Wr[e0]
// y=2: hl_b = xt@Wl[e1];  y=3: hr_b = xs@Wr[e1]

__device__ inline half8 ldA8(const _Float16* p) { return *(const half8*)p; }
__device__ inline half8 ldA8(const float* p) {
    float4 a = *(const float4*)p;
    float4 b = *(const float4*)(p + 4);
    half8 r = {(_Float16)a.x, (_Float16)a.y, (_Float16)a.z, (_Float16)a.w,
               (_Float16)b.x, (_Float16)b.y, (_Float16)b.z, (_Float16)b.w};
    return r;
}

template <typename AT>
__global__ void __launch_bounds__(256)
gemm_f16(const AT* __restrict__ xs, const AT* __restrict__ xt,
         const _Float16* __restrict__ WtL, const _Float16* __restrict__ WtR,
         const float* __restrict__ bl, const float* __restrict__ br,
         _Float16* __restrict__ hbase, int e0) {
    const int y = blockIdx.y;
    const int e = e0 + (y >> 1);
    const AT* A = (y == 0 || y == 3) ? xs : xt;
    const bool left = (y & 1) == 0;
    const _Float16* Wt = (left ? WtL : WtR) + (size_t)e * 65536;
    const float* bvec = (left ? bl : br) + (size_t)e * HC;
    _Float16* C = hbase + (size_t)y * NFE;

    __shared__ __align__(16) _Float16 As[64 * 32];
    __shared__ __align__(16) _Float16 Bs[256 * 32];

    const int t = threadIdx.x;
    const int lane = t & 63, w = t >> 6;
    const int m0 = blockIdx.x * 64;
    const int rl = lane & 15, ch = lane >> 4;
    const int ar = t >> 2, ac = t & 3;

    floatx4 acc[4][4] = {};

    for (int k0 = 0; k0 < 256; k0 += 32) {
        half8 av = {};
        {
            int gr = m0 + ar;
            if (gr < NNODES) av = ldA8(A + (size_t)gr * 256 + k0 + ac * 8);
        }
        half8 bv[4];
#pragma unroll
        for (int j = 0; j < 4; j++) {
            int n = ar + j * 64;
            bv[j] = *(const half8*)(Wt + (size_t)n * 256 + k0 + ac * 8);
        }
        __syncthreads();
        *(half8*)(As + ar * 32 + (ac ^ ((ar >> 1) & 3)) * 8) = av;
#pragma unroll
        for (int j = 0; j < 4; j++) {
            int n = ar + j * 64;
            *(half8*)(Bs + n * 32 + (ac ^ ((n >> 1) & 3)) * 8) = bv[j];
        }
        __syncthreads();

        half8 a[4], b[4];
#pragma unroll
        for (int fm = 0; fm < 4; fm++) {
            int r = fm * 16 + rl;
            a[fm] = *(const half8*)(As + r * 32 + (ch ^ ((r >> 1) & 3)) * 8);
        }
#pragma unroll
        for (int fn = 0; fn < 4; fn++) {
            int n = w * 64 + fn * 16 + rl;
            b[fn] = *(const half8*)(Bs + n * 32 + (ch ^ ((n >> 1) & 3)) * 8);
        }
#pragma unroll
        for (int fm = 0; fm < 4; fm++)
#pragma unroll
            for (int fn = 0; fn < 4; fn++)
                acc[fm][fn] = __builtin_amdgcn_mfma_f32_16x16x32_f16(a[fm], b[fn], acc[fm][fn], 0, 0, 0);
    }

#pragma unroll
    for (int fn = 0; fn < 4; fn++) {
        int colb = w * 64 + fn * 16 + rl;
        float bb = bvec[colb];
#pragma unroll
        for (int fm = 0; fm < 4; fm++) {
#pragma unroll
            for (int j = 0; j < 4; j++) {
                int row = m0 + fm * 16 + ch * 4 + j;
                if (row < NNODES) C[(size_t)row * 256 + colb] = (_Float16)(acc[fm][fn][j] + bb);
            }
        }
    }
}

// ---------------- fused attention + aggregate (packed fp16 math) ----------------

__device__ inline void store4(float* p, float4 v) { *(float4*)p = v; }
__device__ inline void store4(_Float16* p, float4 v) {
    h4v h = {(_Float16)v.x, (_Float16)v.y, (_Float16)v.z, (_Float16)v.w};
    *(h4v*)p = h;
}

template <typename OT>
__global__ void __launch_bounds__(256)
agg_kernel(const _Float16* __restrict__ hbase,
           const int* __restrict__ rp_dst, const unsigned short* __restrict__ col_dst,
           const int* __restrict__ rp_src, const unsigned short* __restrict__ col_src,
           const float* __restrict__ att, const float* __restrict__ bias,
           OT* __restrict__ out0, OT* __restrict__ out1, int e0, int do_relu) {
    const int z = blockIdx.y;
    const _Float16* hl = hbase + (size_t)z * 2 * NFE;
    const _Float16* hr = hl + NFE;
    const int* rp = z ? rp_src : rp_dst;
    const unsigned short* col = z ? col_src : col_dst;
    const float* attz = att + (size_t)(e0 + z) * HC;
    const float* biasz = bias + (size_t)(e0 + z) * HC;
    OT* out = z ? out1 : out0;

    int wave = threadIdx.x >> 6;
    int lane = threadIdx.x & 63;
    int n = blockIdx.x * 4 + wave;
    if (n >= NNODES) return;

    int c4 = lane << 2;
    h4v hr4 = *(const h4v*)(hr + (size_t)n * HC + c4);
    h2 hrA = {hr4[0], hr4[1]};
    h2 hrB = {hr4[2], hr4[3]};
    float4 att4 = *(const float4*)(attz + c4);
    float4 b4 = *(const float4*)(biasz + c4);
    const h2 negv = {(_Float16)NEG_SLOPE, (_Float16)NEG_SLOPE};

    float a0 = 0.f, a1 = 0.f, a2 = 0.f, a3 = 0.f, denom = 0.f;

#define EDGE(h4x)                                                   \
    {                                                               \
        h2 pa = {h4x[0], h4x[1]};                                   \
        h2 pb = {h4x[2], h4x[3]};                                   \
        h2 xa = pa + hrA, xb = pb + hrB;                            \
        h2 la = __builtin_elementwise_max(xa, xa * negv);           \
        h2 lb = __builtin_elementwise_max(xb, xb * negv);           \
        float v = (float)la[0] * att4.x;                            \
        v = fmaf((float)la[1], att4.y, v);                          \
        v = fmaf((float)lb[0], att4.z, v);                          \
        v = fmaf((float)lb[1], att4.w, v);                          \
        v += __shfl_xor(v, 1);                                      \
        v += __shfl_xor(v, 2);                                      \
        v += __shfl_xor(v, 4);                                      \
        float pe = __expf(v);                                       \
        denom += pe;                                                \
        a0 = fmaf((float)h4x[0], pe, a0);                           \
        a1 = fmaf((float)h4x[1], pe, a1);                           \
        a2 = fmaf((float)h4x[2], pe, a2);                           \
        a3 = fmaf((float)h4x[3], pe, a3);                           \
    }

    for (int pp = 0; pp < NPART; pp++) {
        int beg = rp[pp * NNODES + n];
        int end = rp[pp * NNODES + n + 1];
        int i = beg;
        for (; i + 2 <= end; i += 2) {
            int s0 = col[i], s1 = col[i + 1];
            h4v h0 = *(const h4v*)(hl + (size_t)s0 * HC + c4);
            h4v h1 = *(const h4v*)(hl + (size_t)s1 * HC + c4);
            EDGE(h0);
            EDGE(h1);
        }
        if (i < end) {
            h4v h0 = *(const h4v*)(hl + (size_t)col[i] * HC + c4);
            EDGE(h0);
        }
    }
#undef EDGE

    float inv = 1.f / (denom + 1e-16f);
    float4 o;
    o.x = a0 * inv + b4.x;
    o.y = a1 * inv + b4.y;
    o.z = a2 * inv + b4.z;
    o.w = a3 * inv + b4.w;
    if (do_relu) {
        o.x = fmaxf(o.x, 0.f);
        o.y = fmaxf(o.y, 0.f);
        o.z = fmaxf(o.z, 0.f);
        o.w = fmaxf(o.w, 0.f);
    }
    store4(out + (size_t)n * HC + c4, o);
}

// ---------------- launch ----------------

extern "C" void kernel_launch(void* const* d_in, const int* in_sizes, int n_in,
                              void* d_out, int out_size, void* d_ws, size_t ws_size,
                              hipStream_t stream) {
    const float* s = (const float*)d_in[0];
    const float* t = (const float*)d_in[1];
    const float* Wl = (const float*)d_in[2];
    const float* bl = (const float*)d_in[3];
    const float* Wr = (const float*)d_in[4];
    const float* br = (const float*)d_in[5];
    const float* att = (const float*)d_in[6];
    const float* bias = (const float*)d_in[7];
    const int* ei = (const int*)d_in[8];
    float* out = (float*)d_out;

    const size_t NF = (size_t)NFE;

    // workspace layout
    _Float16* os16 = (_Float16*)d_ws;         // NF (layer-0 agg out, source dir)
    _Float16* ot16 = os16 + NF;               // NF (layer-0 agg out, target dir)
    _Float16* hbase = ot16 + NF;              // 4*NF (hl_a, hr_a, hl_b, hr_b)
    _Float16* WtL = hbase + 4 * NF;           // 4*65536
    _Float16* WtR = WtL + 4 * 65536;          // 4*65536
    int* deg_dst = (int*)(WtR + 4 * 65536);   // PN
    int* deg_src = deg_dst + PN;              // PN
    int* rp_dst = deg_src + PN;               // PN+1
    int* rp_src = rp_dst + (PN + 1);          // PN+1
    int* cur_dst = rp_src + (PN + 1);         // PN
    int* cur_src = cur_dst + PN;              // PN
    int* bsum = cur_src + PN;                 // 512
    unsigned short* col_dst = (unsigned short*)(bsum + 512);  // E
    unsigned short* col_src = col_dst + NEDGES;               // E

    // ---- CSR build + weight prep ----
    hipMemsetAsync(deg_dst, 0, 2 * PN * sizeof(int), stream);
    prep_kernel<<<512 + NPART * CPP, 256, 0, stream>>>(Wl, Wr, WtL, WtR, ei, deg_dst, deg_src);
    {
        dim3 g(NCHUNK2, 2);
        scan1_kernel<<<g, SCAN_CHUNK, 0, stream>>>(deg_dst, deg_src, rp_dst, rp_src,
                                                   cur_dst, cur_src, bsum);
        scan2_kernel<<<1, 64, 0, stream>>>(bsum);
        scan3_kernel<<<g, SCAN_CHUNK, 0, stream>>>(rp_dst, rp_src, cur_dst, cur_src, bsum);
    }
    fill_kernel<<<NPART * CPP, 256, 0, stream>>>(ei, cur_dst, cur_src, col_dst, col_src);

    dim3 ggemm((NNODES + 63) / 64, 4);
    dim3 gagg((NNODES + 3) / 4, 2);

    // layer 0 (fp32 inputs, relu)
    gemm_f16<float><<<ggemm, 256, 0, stream>>>(s, t, WtL, WtR, bl, br, hbase, 0);
    agg_kernel<_Float16><<<gagg, 256, 0, stream>>>(hbase, rp_dst, col_dst, rp_src, col_src,
                                                   att, bias, os16, ot16, 0, 1);
    // layer 1 (fp16 inputs, identity, fp32 out)
    gemm_f16<_Float16><<<ggemm, 256, 0, stream>>>(os16, ot16, WtL, WtR, bl, br, hbase, 2);
    agg_kernel<float><<<gagg, 256, 0, stream>>>(hbase, rp_dst, col_dst, rp_src, col_src,
                                                att, bias, out, out + NF, 2, 0);
}

// Round 5
// 393.910 us; speedup vs baseline: 1.1597x; 1.1062x over previous
//
#include <hip/hip_runtime.h>
#include <hip/hip_bf16.h>

#define NNODES 30000
#define NEDGES 480000
#define HC 256
#define NEG_SLOPE 0.2f
#define NPART 8
#define EPP 60000                 // NEDGES / NPART
#define PN (NPART * NNODES)       // 240000
#define SCAN_CHUNK 1024
#define NCHUNK2 235               // ceil(PN / 1024)
#define NCHUNKM 30                // ceil(NNODES / 1024)
#define CPP 235                   // ceil(EPP / 256)
#define NFE 7680000               // NNODES * HC

typedef _Float16 half8 __attribute__((ext_vector_type(8)));
typedef _Float16 h4v __attribute__((ext_vector_type(4)));
typedef _Float16 h2 __attribute__((ext_vector_type(2)));
typedef float floatx4 __attribute__((ext_vector_type(4)));

// ---------------- prep: weight transpose+cvt (blocks 0..511) | edge histogram (rest) ----------------

__global__ void prep_kernel(const float* __restrict__ Wl, const float* __restrict__ Wr,
                            _Float16* __restrict__ WtL, _Float16* __restrict__ WtR,
                            const int* __restrict__ ei, int* __restrict__ deg_dst,
                            int* __restrict__ deg_src) {
    __shared__ float sh[32][33];
    int b = blockIdx.x;
    if (b < 512) {
        int e = b >> 6;
        int r0 = ((b >> 3) & 7) * 32, c0 = (b & 7) * 32;
        const float* W = (e < 4) ? Wl + (size_t)e * 65536 : Wr + (size_t)(e - 4) * 65536;
        _Float16* Wt = (e < 4) ? WtL + (size_t)e * 65536 : WtR + (size_t)(e - 4) * 65536;
        int x = threadIdx.x & 31, y = threadIdx.x >> 5;  // 32 x 8
#pragma unroll
        for (int j = 0; j < 4; j++) {
            int r = y + j * 8;
            sh[r][x] = W[(size_t)(r0 + r) * 256 + c0 + x];
        }
        __syncthreads();
#pragma unroll
        for (int j = 0; j < 4; j++) {
            int nn = y + j * 8;
            Wt[(size_t)(c0 + nn) * 256 + r0 + x] = (_Float16)sh[x][nn];
        }
    } else {
        b -= 512;
        int p = b & 7, c = b >> 3;
        int idx = c * 256 + threadIdx.x;
        if (idx >= EPP) return;
        int e = p * EPP + idx;
        int s = ei[e];
        int d = ei[NEDGES + e];
        atomicAdd(&deg_dst[p * NNODES + d], 1);
        atomicAdd(&deg_src[p * NNODES + s], 1);
    }
}

// mdeg[z][n] = sum_p deg[z][p*N+n]
__global__ void mdeg_kernel(const int* __restrict__ deg_dst, const int* __restrict__ deg_src,
                            int* __restrict__ mdeg_dst, int* __restrict__ mdeg_src) {
    const int* deg = blockIdx.y ? deg_src : deg_dst;
    int* mdeg = blockIdx.y ? mdeg_src : mdeg_dst;
    int n = blockIdx.x * blockDim.x + threadIdx.x;
    if (n >= NNODES) return;
    int s = 0;
#pragma unroll
    for (int p = 0; p < NPART; p++) s += deg[p * NNODES + n];
    mdeg[n] = s;
}

// ---------------- scans ----------------
// jobs: y=0 deg_dst->cur_dst (PN, exclusive), y=1 deg_src->cur_src,
//       y=2 mdeg_dst->mrp_dst[1..] (N, inclusive), y=3 mdeg_src->mrp_src[1..]

__global__ void scanA_kernel(const int* __restrict__ deg_dst, const int* __restrict__ deg_src,
                             const int* __restrict__ mdeg_dst, const int* __restrict__ mdeg_src,
                             int* __restrict__ cur_dst, int* __restrict__ cur_src,
                             int* __restrict__ mrp_dst, int* __restrict__ mrp_src,
                             int* __restrict__ bsum) {
    __shared__ int sh[SCAN_CHUNK];
    const int y = blockIdx.y;
    const int nelem = (y < 2) ? PN : NNODES;
    if (blockIdx.x * SCAN_CHUNK >= nelem) return;
    const int* in = (y == 0) ? deg_dst : (y == 1) ? deg_src : (y == 2) ? mdeg_dst : mdeg_src;
    int t = threadIdx.x;
    int gid = blockIdx.x * SCAN_CHUNK + t;
    int v = (gid < nelem) ? in[gid] : 0;
    sh[t] = v;
    __syncthreads();
    for (int off = 1; off < SCAN_CHUNK; off <<= 1) {
        int u = (t >= off) ? sh[t - off] : 0;
        __syncthreads();
        sh[t] += u;
        __syncthreads();
    }
    if (gid < nelem) {
        if (y < 2) {
            int* cur = (y == 0) ? cur_dst : cur_src;
            cur[gid] = sh[t] - v;
        } else {
            int* mrp = (y == 2) ? mrp_dst : mrp_src;
            mrp[gid + 1] = sh[t];
        }
    }
    if (t == SCAN_CHUNK - 1) bsum[y * 256 + blockIdx.x] = sh[t];
}

__global__ void scan2_kernel(int* __restrict__ bsum) {
    int t = threadIdx.x;
    if (t < 4) {
        int cnt = (t < 2) ? NCHUNK2 : NCHUNKM;
        int run = 0;
        for (int i = 0; i < cnt; i++) {
            int v = bsum[t * 256 + i];
            bsum[t * 256 + i] = run;
            run += v;
        }
    }
}

__global__ void scanB_kernel(int* __restrict__ cur_dst, int* __restrict__ cur_src,
                             int* __restrict__ mrp_dst, int* __restrict__ mrp_src,
                             const int* __restrict__ bsum) {
    const int y = blockIdx.y;
    const int nelem = (y < 2) ? PN : NNODES;
    if (blockIdx.x * SCAN_CHUNK >= nelem) return;
    int t = threadIdx.x;
    int gid = blockIdx.x * SCAN_CHUNK + t;
    int base = bsum[y * 256 + blockIdx.x];
    if (gid < nelem) {
        if (y < 2) {
            ((y == 0) ? cur_dst : cur_src)[gid] += base;
        } else {
            ((y == 2) ? mrp_dst : mrp_src)[gid + 1] += base;
        }
    }
    if (gid == 0 && y >= 2) ((y == 2) ? mrp_dst : mrp_src)[0] = 0;
}

__global__ void fill_kernel(const int* __restrict__ ei, int* __restrict__ cur_dst,
                            int* __restrict__ cur_src, unsigned short* __restrict__ col_dst,
                            unsigned short* __restrict__ col_src) {
    int p = blockIdx.x & 7, c = blockIdx.x >> 3;
    int idx = c * 256 + threadIdx.x;
    if (idx >= EPP) return;
    int e = p * EPP + idx;
    int s = ei[e];
    int d = ei[NEDGES + e];
    int p0 = atomicAdd(&cur_dst[p * NNODES + d], 1);
    col_dst[p0] = (unsigned short)s;
    int p1 = atomicAdd(&cur_src[p * NNODES + s], 1);
    col_src[p1] = (unsigned short)d;
}

// merge 8 part-segments of each node into node-contiguous mcol (after fill: cur = segment ends)
__global__ void merge_kernel(const int* __restrict__ deg_dst, const int* __restrict__ deg_src,
                             const int* __restrict__ cur_dst, const int* __restrict__ cur_src,
                             const int* __restrict__ mrp_dst, const int* __restrict__ mrp_src,
                             const unsigned short* __restrict__ col_dst,
                             const unsigned short* __restrict__ col_src,
                             unsigned short* __restrict__ mcol_dst,
                             unsigned short* __restrict__ mcol_src) {
    const int z = blockIdx.y;
    const int* deg = z ? deg_src : deg_dst;
    const int* cur = z ? cur_src : cur_dst;
    const int* mrp = z ? mrp_src : mrp_dst;
    const unsigned short* col = z ? col_src : col_dst;
    unsigned short* mcol = z ? mcol_src : mcol_dst;
    int n = blockIdx.x * blockDim.x + threadIdx.x;
    if (n >= NNODES) return;
    int w = mrp[n];
#pragma unroll
    for (int p = 0; p < NPART; p++) {
        int e = cur[p * NNODES + n];
        int d = deg[p * NNODES + n];
        for (int k = e - d; k < e; k++) mcol[w++] = col[k];
    }
}

// ---------------- fp16 MFMA GEMM (4 GEMMs fused via grid.y; A-dtype templated) ----------------

__device__ inline half8 ldA8(const _Float16* p) { return *(const half8*)p; }
__device__ inline half8 ldA8(const float* p) {
    float4 a = *(const float4*)p;
    float4 b = *(const float4*)(p + 4);
    half8 r = {(_Float16)a.x, (_Float16)a.y, (_Float16)a.z, (_Float16)a.w,
               (_Float16)b.x, (_Float16)b.y, (_Float16)b.z, (_Float16)b.w};
    return r;
}

template <typename AT>
__global__ void __launch_bounds__(256)
gemm_f16(const AT* __restrict__ xs, const AT* __restrict__ xt,
         const _Float16* __restrict__ WtL, const _Float16* __restrict__ WtR,
         const float* __restrict__ bl, const float* __restrict__ br,
         _Float16* __restrict__ hbase, int e0) {
    const int y = blockIdx.y;
    const int e = e0 + (y >> 1);
    const AT* A = (y == 0 || y == 3) ? xs : xt;
    const bool left = (y & 1) == 0;
    const _Float16* Wt = (left ? WtL : WtR) + (size_t)e * 65536;
    const float* bvec = (left ? bl : br) + (size_t)e * HC;
    _Float16* C = hbase + (size_t)y * NFE;

    __shared__ __align__(16) _Float16 As[64 * 32];
    __shared__ __align__(16) _Float16 Bs[256 * 32];

    const int t = threadIdx.x;
    const int lane = t & 63, w = t >> 6;
    const int m0 = blockIdx.x * 64;
    const int rl = lane & 15, ch = lane >> 4;
    const int ar = t >> 2, ac = t & 3;

    floatx4 acc[4][4] = {};

    for (int k0 = 0; k0 < 256; k0 += 32) {
        half8 av = {};
        {
            int gr = m0 + ar;
            if (gr < NNODES) av = ldA8(A + (size_t)gr * 256 + k0 + ac * 8);
        }
        half8 bv[4];
#pragma unroll
        for (int j = 0; j < 4; j++) {
            int n = ar + j * 64;
            bv[j] = *(const half8*)(Wt + (size_t)n * 256 + k0 + ac * 8);
        }
        __syncthreads();
        *(half8*)(As + ar * 32 + (ac ^ ((ar >> 1) & 3)) * 8) = av;
#pragma unroll
        for (int j = 0; j < 4; j++) {
            int n = ar + j * 64;
            *(half8*)(Bs + n * 32 + (ac ^ ((n >> 1) & 3)) * 8) = bv[j];
        }
        __syncthreads();

        half8 a[4], b[4];
#pragma unroll
        for (int fm = 0; fm < 4; fm++) {
            int r = fm * 16 + rl;
            a[fm] = *(const half8*)(As + r * 32 + (ch ^ ((r >> 1) & 3)) * 8);
        }
#pragma unroll
        for (int fn = 0; fn < 4; fn++) {
            int n = w * 64 + fn * 16 + rl;
            b[fn] = *(const half8*)(Bs + n * 32 + (ch ^ ((n >> 1) & 3)) * 8);
        }
#pragma unroll
        for (int fm = 0; fm < 4; fm++)
#pragma unroll
            for (int fn = 0; fn < 4; fn++)
                acc[fm][fn] = __builtin_amdgcn_mfma_f32_16x16x32_f16(a[fm], b[fn], acc[fm][fn], 0, 0, 0);
    }

#pragma unroll
    for (int fn = 0; fn < 4; fn++) {
        int colb = w * 64 + fn * 16 + rl;
        float bb = bvec[colb];
#pragma unroll
        for (int fm = 0; fm < 4; fm++) {
#pragma unroll
            for (int j = 0; j < 4; j++) {
                int row = m0 + fm * 16 + ch * 4 + j;
                if (row < NNODES) C[(size_t)row * 256 + colb] = (_Float16)(acc[fm][fn][j] + bb);
            }
        }
    }
}

// ---------------- fused attention + aggregate (2 edges per wave, 8ch/lane) ----------------

__device__ __forceinline__ void edge_body(half8 hv, half8 hrv, const float* att8,
                                          float* acc, float& denom, bool valid) {
    const h2 negv = {(_Float16)NEG_SLOPE, (_Float16)NEG_SLOPE};
    const h2* hvp = (const h2*)&hv;
    const h2* hrp = (const h2*)&hrv;
    float v = 0.f;
#pragma unroll
    for (int k = 0; k < 4; k++) {
        h2 x = hvp[k] + hrp[k];
        h2 lk = __builtin_elementwise_max(x, x * negv);
        v = fmaf((float)lk[0], att8[2 * k], v);
        v = fmaf((float)lk[1], att8[2 * k + 1], v);
    }
    v += __shfl_xor(v, 1);
    v += __shfl_xor(v, 2);
    float pe = __expf(v);
    if (!valid) pe = 0.f;
    denom += pe;
#pragma unroll
    for (int k = 0; k < 8; k++) acc[k] = fmaf((float)hv[k], pe, acc[k]);
}

__device__ inline void store8(float* p, const float* o) {
    *(float4*)p = make_float4(o[0], o[1], o[2], o[3]);
    *(float4*)(p + 4) = make_float4(o[4], o[5], o[6], o[7]);
}
__device__ inline void store8(_Float16* p, const float* o) {
    half8 h = {(_Float16)o[0], (_Float16)o[1], (_Float16)o[2], (_Float16)o[3],
               (_Float16)o[4], (_Float16)o[5], (_Float16)o[6], (_Float16)o[7]};
    *(half8*)p = h;
}

template <typename OT>
__global__ void __launch_bounds__(256)
agg_kernel(const _Float16* __restrict__ hbase,
           const int* __restrict__ mrp_dst, const unsigned short* __restrict__ mcol_dst,
           const int* __restrict__ mrp_src, const unsigned short* __restrict__ mcol_src,
           const float* __restrict__ att, const float* __restrict__ bias,
           OT* __restrict__ out0, OT* __restrict__ out1, int e0, int do_relu) {
    const int z = blockIdx.y;
    const _Float16* hl = hbase + (size_t)z * 2 * NFE;
    const _Float16* hr = hl + NFE;
    const int* mrp = z ? mrp_src : mrp_dst;
    const unsigned short* mcol = z ? mcol_src : mcol_dst;
    const float* attz = att + (size_t)(e0 + z) * HC;
    const float* biasz = bias + (size_t)(e0 + z) * HC;
    OT* out = z ? out1 : out0;

    int wave = threadIdx.x >> 6;
    int lane = threadIdx.x & 63;
    int n = blockIdx.x * 4 + wave;
    if (n >= NNODES) return;
    int h = lane >> 5;       // edge parity within the wave
    int cl = lane & 31;      // channel block (8 channels)
    int c8 = cl << 3;

    half8 hrv = *(const half8*)(hr + (size_t)n * HC + c8);
    float att8[8];
    *(float4*)(att8) = *(const float4*)(attz + c8);
    *(float4*)(att8 + 4) = *(const float4*)(attz + c8 + 4);

    float acc[8] = {};
    float denom = 0.f;
    int beg = mrp[n], end = mrp[n + 1];

    int i = beg;
    for (; i + 4 <= end; i += 4) {
        int s0 = (int)mcol[i + h];
        int s1 = (int)mcol[i + 2 + h];
        half8 hv0 = *(const half8*)(hl + (size_t)s0 * HC + c8);
        half8 hv1 = *(const half8*)(hl + (size_t)s1 * HC + c8);
        edge_body(hv0, hrv, att8, acc, denom, true);
        edge_body(hv1, hrv, att8, acc, denom, true);
    }
    for (; i < end; i += 2) {
        int ei = i + h;
        bool valid = ei < end;
        int s0 = (int)mcol[valid ? ei : end - 1];
        half8 hv0 = *(const half8*)(hl + (size_t)s0 * HC + c8);
        edge_body(hv0, hrv, att8, acc, denom, valid);
    }

    // merge the two half-wave partials
#pragma unroll
    for (int k = 0; k < 8; k++) acc[k] += __shfl_xor(acc[k], 32);
    denom += __shfl_xor(denom, 32);

    if (lane < 32) {
        float inv = 1.f / (denom + 1e-16f);
        float o[8];
        float b8[8];
        *(float4*)(b8) = *(const float4*)(biasz + c8);
        *(float4*)(b8 + 4) = *(const float4*)(biasz + c8 + 4);
#pragma unroll
        for (int k = 0; k < 8; k++) {
            o[k] = acc[k] * inv + b8[k];
            if (do_relu) o[k] = fmaxf(o[k], 0.f);
        }
        store8(out + (size_t)n * HC + c8, o);
    }
}

// ---------------- launch ----------------

extern "C" void kernel_launch(void* const* d_in, const int* in_sizes, int n_in,
                              void* d_out, int out_size, void* d_ws, size_t ws_size,
                              hipStream_t stream) {
    const float* s = (const float*)d_in[0];
    const float* t = (const float*)d_in[1];
    const float* Wl = (const float*)d_in[2];
    const float* bl = (const float*)d_in[3];
    const float* Wr = (const float*)d_in[4];
    const float* br = (const float*)d_in[5];
    const float* att = (const float*)d_in[6];
    const float* bias = (const float*)d_in[7];
    const int* ei = (const int*)d_in[8];
    float* out = (float*)d_out;

    const size_t NF = (size_t)NFE;

    // workspace layout
    _Float16* os16 = (_Float16*)d_ws;         // NF
    _Float16* ot16 = os16 + NF;               // NF
    _Float16* hbase = ot16 + NF;              // 4*NF
    _Float16* WtL = hbase + 4 * NF;           // 4*65536
    _Float16* WtR = WtL + 4 * 65536;          // 4*65536
    int* deg_dst = (int*)(WtR + 4 * 65536);   // PN
    int* deg_src = deg_dst + PN;              // PN
    int* cur_dst = deg_src + PN;              // PN
    int* cur_src = cur_dst + PN;              // PN
    int* mdeg_dst = cur_src + PN;             // N
    int* mdeg_src = mdeg_dst + NNODES;        // N
    int* mrp_dst = mdeg_src + NNODES;         // N+1
    int* mrp_src = mrp_dst + (NNODES + 1);    // N+1
    int* bsum = mrp_src + (NNODES + 1);       // 1024
    unsigned short* col_dst = (unsigned short*)(bsum + 1024);  // E
    unsigned short* col_src = col_dst + NEDGES;                // E
    unsigned short* mcol_dst = col_src + NEDGES;               // E
    unsigned short* mcol_src = mcol_dst + NEDGES;              // E

    // ---- CSR build + weight prep ----
    hipMemsetAsync(deg_dst, 0, 2 * PN * sizeof(int), stream);
    prep_kernel<<<512 + NPART * CPP, 256, 0, stream>>>(Wl, Wr, WtL, WtR, ei, deg_dst, deg_src);
    mdeg_kernel<<<dim3(118, 2), 256, 0, stream>>>(deg_dst, deg_src, mdeg_dst, mdeg_src);
    {
        dim3 g(NCHUNK2, 4);
        scanA_kernel<<<g, SCAN_CHUNK, 0, stream>>>(deg_dst, deg_src, mdeg_dst, mdeg_src,
                                                   cur_dst, cur_src, mrp_dst, mrp_src, bsum);
        scan2_kernel<<<1, 64, 0, stream>>>(bsum);
        scanB_kernel<<<g, SCAN_CHUNK, 0, stream>>>(cur_dst, cur_src, mrp_dst, mrp_src, bsum);
    }
    fill_kernel<<<NPART * CPP, 256, 0, stream>>>(ei, cur_dst, cur_src, col_dst, col_src);
    merge_kernel<<<dim3(118, 2), 256, 0, stream>>>(deg_dst, deg_src, cur_dst, cur_src,
                                                   mrp_dst, mrp_src, col_dst, col_src,
                                                   mcol_dst, mcol_src);

    dim3 ggemm((NNODES + 63) / 64, 4);
    dim3 gagg((NNODES + 3) / 4, 2);

    // layer 0 (fp32 inputs, relu)
    gemm_f16<float><<<ggemm, 256, 0, stream>>>(s, t, WtL, WtR, bl, br, hbase, 0);
    agg_kernel<_Float16><<<gagg, 256, 0, stream>>>(hbase, mrp_dst, mcol_dst, mrp_src, mcol_src,
                                                   att, bias, os16, ot16, 0, 1);
    // layer 1 (fp16 inputs, identity, fp32 out)
    gemm_f16<_Float16><<<ggemm, 256, 0, stream>>>(os16, ot16, WtL, WtR, bl, br, hbase, 2);
    agg_kernel<float><<<gagg, 256, 0, stream>>>(hbase, mrp_dst, mcol_dst, mrp_src, mcol_src,
                                                att, bias, out, out + NF, 2, 0);
}

// Round 6
// 377.586 us; speedup vs baseline: 1.2098x; 1.0432x over previous
//
#include <hip/hip_runtime.h>
#include <hip/hip_bf16.h>

#define NNODES 30000
#define NEDGES 480000
#define HC 256
#define NEG_SLOPE 0.2f
#define NPART 8
#define EPP 60000                 // NEDGES / NPART
#define PN (NPART * NNODES)       // 240000
#define SCAN_CHUNK 1024
#define NCHUNK2 235               // ceil(PN / 1024)
#define NCHUNKM 30                // ceil(NNODES / 1024)
#define CPP 235                   // ceil(EPP / 256)
#define NFE 7680000               // NNODES * HC

typedef _Float16 half8 __attribute__((ext_vector_type(8)));
typedef _Float16 h4v __attribute__((ext_vector_type(4)));
typedef _Float16 h2 __attribute__((ext_vector_type(2)));
typedef float floatx4 __attribute__((ext_vector_type(4)));

// ---------------- prep: weight transpose+cvt (blocks 0..511) | edge histogram (rest) ----------------

__global__ void prep_kernel(const float* __restrict__ Wl, const float* __restrict__ Wr,
                            _Float16* __restrict__ WtL, _Float16* __restrict__ WtR,
                            const int* __restrict__ ei, int* __restrict__ deg_dst,
                            int* __restrict__ deg_src) {
    __shared__ float sh[32][33];
    int b = blockIdx.x;
    if (b < 512) {
        int e = b >> 6;
        int r0 = ((b >> 3) & 7) * 32, c0 = (b & 7) * 32;
        const float* W = (e < 4) ? Wl + (size_t)e * 65536 : Wr + (size_t)(e - 4) * 65536;
        _Float16* Wt = (e < 4) ? WtL + (size_t)e * 65536 : WtR + (size_t)(e - 4) * 65536;
        int x = threadIdx.x & 31, y = threadIdx.x >> 5;  // 32 x 8
#pragma unroll
        for (int j = 0; j < 4; j++) {
            int r = y + j * 8;
            sh[r][x] = W[(size_t)(r0 + r) * 256 + c0 + x];
        }
        __syncthreads();
#pragma unroll
        for (int j = 0; j < 4; j++) {
            int nn = y + j * 8;
            Wt[(size_t)(c0 + nn) * 256 + r0 + x] = (_Float16)sh[x][nn];
        }
    } else {
        b -= 512;
        int p = b & 7, c = b >> 3;
        int idx = c * 256 + threadIdx.x;
        if (idx >= EPP) return;
        int e = p * EPP + idx;
        int s = ei[e];
        int d = ei[NEDGES + e];
        atomicAdd(&deg_dst[p * NNODES + d], 1);
        atomicAdd(&deg_src[p * NNODES + s], 1);
    }
}

// mdeg[z][n] = sum_p deg[z][p*N+n]
__global__ void mdeg_kernel(const int* __restrict__ deg_dst, const int* __restrict__ deg_src,
                            int* __restrict__ mdeg_dst, int* __restrict__ mdeg_src) {
    const int* deg = blockIdx.y ? deg_src : deg_dst;
    int* mdeg = blockIdx.y ? mdeg_src : mdeg_dst;
    int n = blockIdx.x * blockDim.x + threadIdx.x;
    if (n >= NNODES) return;
    int s = 0;
#pragma unroll
    for (int p = 0; p < NPART; p++) s += deg[p * NNODES + n];
    mdeg[n] = s;
}

// ---------------- scans ----------------
// jobs: y=0 deg_dst->cur_dst (PN, exclusive), y=1 deg_src->cur_src,
//       y=2 mdeg_dst->mrp_dst[1..] (N, inclusive), y=3 mdeg_src->mrp_src[1..]

__global__ void scanA_kernel(const int* __restrict__ deg_dst, const int* __restrict__ deg_src,
                             const int* __restrict__ mdeg_dst, const int* __restrict__ mdeg_src,
                             int* __restrict__ cur_dst, int* __restrict__ cur_src,
                             int* __restrict__ mrp_dst, int* __restrict__ mrp_src,
                             int* __restrict__ bsum) {
    __shared__ int sh[SCAN_CHUNK];
    const int y = blockIdx.y;
    const int nelem = (y < 2) ? PN : NNODES;
    if (blockIdx.x * SCAN_CHUNK >= nelem) return;
    const int* in = (y == 0) ? deg_dst : (y == 1) ? deg_src : (y == 2) ? mdeg_dst : mdeg_src;
    int t = threadIdx.x;
    int gid = blockIdx.x * SCAN_CHUNK + t;
    int v = (gid < nelem) ? in[gid] : 0;
    sh[t] = v;
    __syncthreads();
    for (int off = 1; off < SCAN_CHUNK; off <<= 1) {
        int u = (t >= off) ? sh[t - off] : 0;
        __syncthreads();
        sh[t] += u;
        __syncthreads();
    }
    if (gid < nelem) {
        if (y < 2) {
            int* cur = (y == 0) ? cur_dst : cur_src;
            cur[gid] = sh[t] - v;
        } else {
            int* mrp = (y == 2) ? mrp_dst : mrp_src;
            mrp[gid + 1] = sh[t];
        }
    }
    if (t == SCAN_CHUNK - 1) bsum[y * 256 + blockIdx.x] = sh[t];
}

__global__ void scan2_kernel(int* __restrict__ bsum) {
    int t = threadIdx.x;
    if (t < 4) {
        int cnt = (t < 2) ? NCHUNK2 : NCHUNKM;
        int run = 0;
        for (int i = 0; i < cnt; i++) {
            int v = bsum[t * 256 + i];
            bsum[t * 256 + i] = run;
            run += v;
        }
    }
}

__global__ void scanB_kernel(int* __restrict__ cur_dst, int* __restrict__ cur_src,
                             int* __restrict__ mrp_dst, int* __restrict__ mrp_src,
                             const int* __restrict__ bsum) {
    const int y = blockIdx.y;
    const int nelem = (y < 2) ? PN : NNODES;
    if (blockIdx.x * SCAN_CHUNK >= nelem) return;
    int t = threadIdx.x;
    int gid = blockIdx.x * SCAN_CHUNK + t;
    int base = bsum[y * 256 + blockIdx.x];
    if (gid < nelem) {
        if (y < 2) {
            ((y == 0) ? cur_dst : cur_src)[gid] += base;
        } else {
            ((y == 2) ? mrp_dst : mrp_src)[gid + 1] += base;
        }
    }
    if (gid == 0 && y >= 2) ((y == 2) ? mrp_dst : mrp_src)[0] = 0;
}

__global__ void fill_kernel(const int* __restrict__ ei, int* __restrict__ cur_dst,
                            int* __restrict__ cur_src, unsigned short* __restrict__ col_dst,
                            unsigned short* __restrict__ col_src) {
    int p = blockIdx.x & 7, c = blockIdx.x >> 3;
    int idx = c * 256 + threadIdx.x;
    if (idx >= EPP) return;
    int e = p * EPP + idx;
    int s = ei[e];
    int d = ei[NEDGES + e];
    int p0 = atomicAdd(&cur_dst[p * NNODES + d], 1);
    col_dst[p0] = (unsigned short)s;
    int p1 = atomicAdd(&cur_src[p * NNODES + s], 1);
    col_src[p1] = (unsigned short)d;
}

// merge 8 part-segments of each node into node-contiguous mcol (after fill: cur = segment ends)
__global__ void merge_kernel(const int* __restrict__ deg_dst, const int* __restrict__ deg_src,
                             const int* __restrict__ cur_dst, const int* __restrict__ cur_src,
                             const int* __restrict__ mrp_dst, const int* __restrict__ mrp_src,
                             const unsigned short* __restrict__ col_dst,
                             const unsigned short* __restrict__ col_src,
                             unsigned short* __restrict__ mcol_dst,
                             unsigned short* __restrict__ mcol_src) {
    const int z = blockIdx.y;
    const int* deg = z ? deg_src : deg_dst;
    const int* cur = z ? cur_src : cur_dst;
    const int* mrp = z ? mrp_src : mrp_dst;
    const unsigned short* col = z ? col_src : col_dst;
    unsigned short* mcol = z ? mcol_src : mcol_dst;
    int n = blockIdx.x * blockDim.x + threadIdx.x;
    if (n >= NNODES) return;
    int w = mrp[n];
#pragma unroll
    for (int p = 0; p < NPART; p++) {
        int e = cur[p * NNODES + n];
        int d = deg[p * NNODES + n];
        for (int k = e - d; k < e; k++) mcol[w++] = col[k];
    }
}

// ---------------- fp16 MFMA GEMM (4 GEMMs fused via grid.y; A-dtype templated) ----------------
// Pipeline: register-prefetch next K-tile during MFMA; epilogue staged via LDS
// so C-stores are 64B-contiguous per thread (fixes 2.1x write amplification).

__device__ inline half8 ldA8(const _Float16* p) { return *(const half8*)p; }
__device__ inline half8 ldA8(const float* p) {
    float4 a = *(const float4*)p;
    float4 b = *(const float4*)(p + 4);
    half8 r = {(_Float16)a.x, (_Float16)a.y, (_Float16)a.z, (_Float16)a.w,
               (_Float16)b.x, (_Float16)b.y, (_Float16)b.z, (_Float16)b.w};
    return r;
}

#define EPI_STRIDE 264  // halfs; 528B: 16B-aligned rows, ch-groups hit distinct-ish banks

template <typename AT>
__global__ void __launch_bounds__(256)
gemm_f16(const AT* __restrict__ xs, const AT* __restrict__ xt,
         const _Float16* __restrict__ WtL, const _Float16* __restrict__ WtR,
         const float* __restrict__ bl, const float* __restrict__ br,
         _Float16* __restrict__ hbase, int e0) {
    const int y = blockIdx.y;
    const int e = e0 + (y >> 1);
    const AT* A = (y == 0 || y == 3) ? xs : xt;
    const bool left = (y & 1) == 0;
    const _Float16* Wt = (left ? WtL : WtR) + (size_t)e * 65536;
    const float* bvec = (left ? bl : br) + (size_t)e * HC;
    _Float16* C = hbase + (size_t)y * NFE;

    __shared__ __align__(16) _Float16 sh[10240];  // As(2048) | Bs(8192); reused by epilogue
    _Float16* As = sh;
    _Float16* Bs = sh + 2048;

    const int t = threadIdx.x;
    const int lane = t & 63, w = t >> 6;
    const int m0 = blockIdx.x * 64;
    const int rl = lane & 15, ch = lane >> 4;
    const int ar = t >> 2, ac = t & 3;

    floatx4 acc[4][4] = {};

    // prologue: load K-tile 0 into registers
    half8 av = {};
    {
        int gr = m0 + ar;
        if (gr < NNODES) av = ldA8(A + (size_t)gr * 256 + ac * 8);
    }
    half8 bv[4];
#pragma unroll
    for (int j = 0; j < 4; j++)
        bv[j] = *(const half8*)(Wt + (size_t)(ar + j * 64) * 256 + ac * 8);

    for (int k0 = 0; k0 < 256; k0 += 32) {
        __syncthreads();  // previous iteration's LDS readers done
        *(half8*)(As + ar * 32 + (ac ^ ((ar >> 1) & 3)) * 8) = av;
#pragma unroll
        for (int j = 0; j < 4; j++) {
            int n = ar + j * 64;
            *(half8*)(Bs + n * 32 + (ac ^ ((n >> 1) & 3)) * 8) = bv[j];
        }
        __syncthreads();

        // prefetch next K-tile (latency hides under ds_read + MFMA below)
        if (k0 + 32 < 256) {
            int gr = m0 + ar;
            if (gr < NNODES) av = ldA8(A + (size_t)gr * 256 + (k0 + 32) + ac * 8);
#pragma unroll
            for (int j = 0; j < 4; j++)
                bv[j] = *(const half8*)(Wt + (size_t)(ar + j * 64) * 256 + (k0 + 32) + ac * 8);
        }

        half8 a[4], b[4];
#pragma unroll
        for (int fm = 0; fm < 4; fm++) {
            int r = fm * 16 + rl;
            a[fm] = *(const half8*)(As + r * 32 + (ch ^ ((r >> 1) & 3)) * 8);
        }
#pragma unroll
        for (int fn = 0; fn < 4; fn++) {
            int n = w * 64 + fn * 16 + rl;
            b[fn] = *(const half8*)(Bs + n * 32 + (ch ^ ((n >> 1) & 3)) * 8);
        }
#pragma unroll
        for (int fm = 0; fm < 4; fm++)
#pragma unroll
            for (int fn = 0; fn < 4; fn++)
                acc[fm][fn] = __builtin_amdgcn_mfma_f32_16x16x32_f16(a[fm], b[fn], acc[fm][fn], 0, 0, 0);
    }

    // epilogue: stage through LDS, store 64B-contiguous per thread
    float bb[4];
#pragma unroll
    for (int fn = 0; fn < 4; fn++) bb[fn] = bvec[w * 64 + fn * 16 + rl];

#pragma unroll
    for (int hh = 0; hh < 2; hh++) {
        __syncthreads();  // prior readers done
#pragma unroll
        for (int f2 = 0; f2 < 2; f2++) {
            int fm = hh * 2 + f2;
#pragma unroll
            for (int fn = 0; fn < 4; fn++) {
                int colb = w * 64 + fn * 16 + rl;
#pragma unroll
                for (int j = 0; j < 4; j++) {
                    int lr = f2 * 16 + ch * 4 + j;  // 0..31
                    sh[lr * EPI_STRIDE + colb] = (_Float16)(acc[fm][fn][j] + bb[fn]);
                }
            }
        }
        __syncthreads();
        int lr = t >> 3;            // 0..31
        int cseg = (t & 7) * 32;    // 8 segments x 32 cols (64B)
        int gr = m0 + hh * 32 + lr;
        if (gr < NNODES) {
#pragma unroll
            for (int q = 0; q < 4; q++)
                *(half8*)(C + (size_t)gr * 256 + cseg + q * 8) =
                    *(const half8*)(sh + lr * EPI_STRIDE + cseg + q * 8);
        }
    }
}

// ---------------- fused attention + aggregate (2 edges/wave, 8-edge unroll) ----------------

__device__ __forceinline__ void edge_body(half8 hv, half8 hrv, const float* att8,
                                          float* acc, float& denom, bool valid) {
    const h2 negv = {(_Float16)NEG_SLOPE, (_Float16)NEG_SLOPE};
    const h2* hvp = (const h2*)&hv;
    const h2* hrp = (const h2*)&hrv;
    float v = 0.f;
#pragma unroll
    for (int k = 0; k < 4; k++) {
        h2 x = hvp[k] + hrp[k];
        h2 lk = __builtin_elementwise_max(x, x * negv);
        v = fmaf((float)lk[0], att8[2 * k], v);
        v = fmaf((float)lk[1], att8[2 * k + 1], v);
    }
    v += __shfl_xor(v, 1);
    v += __shfl_xor(v, 2);
    float pe = __expf(v);
    if (!valid) pe = 0.f;
    denom += pe;
#pragma unroll
    for (int k = 0; k < 8; k++) acc[k] = fmaf((float)hv[k], pe, acc[k]);
}

__device__ inline void store8(float* p, const float* o) {
    *(float4*)p = make_float4(o[0], o[1], o[2], o[3]);
    *(float4*)(p + 4) = make_float4(o[4], o[5], o[6], o[7]);
}
__device__ inline void store8(_Float16* p, const float* o) {
    half8 h = {(_Float16)o[0], (_Float16)o[1], (_Float16)o[2], (_Float16)o[3],
               (_Float16)o[4], (_Float16)o[5], (_Float16)o[6], (_Float16)o[7]};
    *(half8*)p = h;
}

template <typename OT>
__global__ void __launch_bounds__(256)
agg_kernel(const _Float16* __restrict__ hbase,
           const int* __restrict__ mrp_dst, const unsigned short* __restrict__ mcol_dst,
           const int* __restrict__ mrp_src, const unsigned short* __restrict__ mcol_src,
           const float* __restrict__ att, const float* __restrict__ bias,
           OT* __restrict__ out0, OT* __restrict__ out1, int e0, int do_relu) {
    const int z = blockIdx.y;
    const _Float16* hl = hbase + (size_t)z * 2 * NFE;
    const _Float16* hr = hl + NFE;
    const int* mrp = z ? mrp_src : mrp_dst;
    const unsigned short* mcol = z ? mcol_src : mcol_dst;
    const float* attz = att + (size_t)(e0 + z) * HC;
    const float* biasz = bias + (size_t)(e0 + z) * HC;
    OT* out = z ? out1 : out0;

    int wave = threadIdx.x >> 6;
    int lane = threadIdx.x & 63;
    int n = blockIdx.x * 4 + wave;
    if (n >= NNODES) return;
    int h = lane >> 5;       // edge parity within the wave
    int cl = lane & 31;      // channel block (8 channels)
    int c8 = cl << 3;

    const _Float16* hlc = hl + c8;
    half8 hrv = *(const half8*)(hr + (size_t)n * HC + c8);
    float att8[8];
    *(float4*)(att8) = *(const float4*)(attz + c8);
    *(float4*)(att8 + 4) = *(const float4*)(attz + c8 + 4);

    float acc[8] = {};
    float denom = 0.f;
    int beg = mrp[n], end = mrp[n + 1];

    int i = beg;
    for (; i + 8 <= end; i += 8) {
        int s0 = (int)mcol[i + h];
        int s1 = (int)mcol[i + 2 + h];
        int s2 = (int)mcol[i + 4 + h];
        int s3 = (int)mcol[i + 6 + h];
        half8 hv0 = *(const half8*)(hlc + ((size_t)s0 << 8));
        half8 hv1 = *(const half8*)(hlc + ((size_t)s1 << 8));
        half8 hv2 = *(const half8*)(hlc + ((size_t)s2 << 8));
        half8 hv3 = *(const half8*)(hlc + ((size_t)s3 << 8));
        edge_body(hv0, hrv, att8, acc, denom, true);
        edge_body(hv1, hrv, att8, acc, denom, true);
        edge_body(hv2, hrv, att8, acc, denom, true);
        edge_body(hv3, hrv, att8, acc, denom, true);
    }
    for (; i + 2 <= end; i += 2) {
        int s0 = (int)mcol[i + h];
        half8 hv0 = *(const half8*)(hlc + ((size_t)s0 << 8));
        edge_body(hv0, hrv, att8, acc, denom, true);
    }
    if (i < end) {
        bool valid = (h == 0);
        int s0 = (int)mcol[i];
        half8 hv0 = *(const half8*)(hlc + ((size_t)s0 << 8));
        edge_body(hv0, hrv, att8, acc, denom, valid);
    }

    // merge the two half-wave partials
#pragma unroll
    for (int k = 0; k < 8; k++) acc[k] += __shfl_xor(acc[k], 32);
    denom += __shfl_xor(denom, 32);

    if (lane < 32) {
        float inv = 1.f / (denom + 1e-16f);
        float o[8];
        float b8[8];
        *(float4*)(b8) = *(const float4*)(biasz + c8);
        *(float4*)(b8 + 4) = *(const float4*)(biasz + c8 + 4);
#pragma unroll
        for (int k = 0; k < 8; k++) {
            o[k] = acc[k] * inv + b8[k];
            if (do_relu) o[k] = fmaxf(o[k], 0.f);
        }
        store8(out + (size_t)n * HC + c8, o);
    }
}

// ---------------- launch ----------------

extern "C" void kernel_launch(void* const* d_in, const int* in_sizes, int n_in,
                              void* d_out, int out_size, void* d_ws, size_t ws_size,
                              hipStream_t stream) {
    const float* s = (const float*)d_in[0];
    const float* t = (const float*)d_in[1];
    const float* Wl = (const float*)d_in[2];
    const float* bl = (const float*)d_in[3];
    const float* Wr = (const float*)d_in[4];
    const float* br = (const float*)d_in[5];
    const float* att = (const float*)d_in[6];
    const float* bias = (const float*)d_in[7];
    const int* ei = (const int*)d_in[8];
    float* out = (float*)d_out;

    const size_t NF = (size_t)NFE;

    // workspace layout
    _Float16* os16 = (_Float16*)d_ws;         // NF
    _Float16* ot16 = os16 + NF;               // NF
    _Float16* hbase = ot16 + NF;              // 4*NF
    _Float16* WtL = hbase + 4 * NF;           // 4*65536
    _Float16* WtR = WtL + 4 * 65536;          // 4*65536
    int* deg_dst = (int*)(WtR + 4 * 65536);   // PN
    int* deg_src = deg_dst + PN;              // PN
    int* cur_dst = deg_src + PN;              // PN
    int* cur_src = cur_dst + PN;              // PN
    int* mdeg_dst = cur_src + PN;             // N
    int* mdeg_src = mdeg_dst + NNODES;        // N
    int* mrp_dst = mdeg_src + NNODES;         // N+1
    int* mrp_src = mrp_dst + (NNODES + 1);    // N+1
    int* bsum = mrp_src + (NNODES + 1);       // 1024
    unsigned short* col_dst = (unsigned short*)(bsum + 1024);  // E
    unsigned short* col_src = col_dst + NEDGES;                // E
    unsigned short* mcol_dst = col_src + NEDGES;               // E
    unsigned short* mcol_src = mcol_dst + NEDGES;              // E

    // ---- CSR build + weight prep ----
    hipMemsetAsync(deg_dst, 0, 2 * PN * sizeof(int), stream);
    prep_kernel<<<512 + NPART * CPP, 256, 0, stream>>>(Wl, Wr, WtL, WtR, ei, deg_dst, deg_src);
    mdeg_kernel<<<dim3(118, 2), 256, 0, stream>>>(deg_dst, deg_src, mdeg_dst, mdeg_src);
    {
        dim3 g(NCHUNK2, 4);
        scanA_kernel<<<g, SCAN_CHUNK, 0, stream>>>(deg_dst, deg_src, mdeg_dst, mdeg_src,
                                                   cur_dst, cur_src, mrp_dst, mrp_src, bsum);
        scan2_kernel<<<1, 64, 0, stream>>>(bsum);
        scanB_kernel<<<g, SCAN_CHUNK, 0, stream>>>(cur_dst, cur_src, mrp_dst, mrp_src, bsum);
    }
    fill_kernel<<<NPART * CPP, 256, 0, stream>>>(ei, cur_dst, cur_src, col_dst, col_src);
    merge_kernel<<<dim3(118, 2), 256, 0, stream>>>(deg_dst, deg_src, cur_dst, cur_src,
                                                   mrp_dst, mrp_src, col_dst, col_src,
                                                   mcol_dst, mcol_src);

    dim3 ggemm((NNODES + 63) / 64, 4);
    dim3 gagg((NNODES + 3) / 4, 2);

    // layer 0 (fp32 inputs, relu)
    gemm_f16<float><<<ggemm, 256, 0, stream>>>(s, t, WtL, WtR, bl, br, hbase, 0);
    agg_kernel<_Float16><<<gagg, 256, 0, stream>>>(hbase, mrp_dst, mcol_dst, mrp_src, mcol_src,
                                                   att, bias, os16, ot16, 0, 1);
    // layer 1 (fp16 inputs, identity, fp32 out)
    gemm_f16<_Float16><<<ggemm, 256, 0, stream>>>(os16, ot16, WtL, WtR, bl, br, hbase, 2);
    agg_kernel<float><<<gagg, 256, 0, stream>>>(hbase, mrp_dst, mcol_dst, mrp_src, mcol_src,
                                                att, bias, out, out + NF, 2, 0);
}